// Round 5
// baseline (244.616 us; speedup 1.0000x reference)
//
#include <hip/hip_runtime.h>
#include <hip/hip_bf16.h>

#define NN 4096
#define KIN 256
#define HF 512
#define NHD 4
#define OF 128

typedef __bf16 bf16x8 __attribute__((ext_vector_type(8)));
typedef __bf16 bf16x4 __attribute__((ext_vector_type(4)));
typedef float f32x4 __attribute__((ext_vector_type(4)));

// ---------------- K0: WT[c][k] = (bf16)W[k][c] ----------------
__global__ __launch_bounds__(256) void k_transpose_w(const float* __restrict__ W,
                                                     __bf16* __restrict__ WT) {
    int idx = blockIdx.x * 256 + threadIdx.x;   // idx = c*256 + k
    int k = idx & 255, c = idx >> 8;
    WT[idx] = (__bf16)W[k * HF + c];
}

// ---------------- K1: hbT[c][m] = sum_k x[m][k]*W[k][c], 16x16x32 MFMA ------
// A[m=lane&15][k=quad*8+j]; B[k][n=lane&15]; C/D col=lane&15, row=quad*4+reg
__global__ __launch_bounds__(256) void k_gemm_h(const float* __restrict__ x,
                                                const __bf16* __restrict__ WT,
                                                __bf16* __restrict__ hbT) {
    int lane = threadIdx.x & 63, wave = threadIdx.x >> 6;
    int m = lane & 15, quad = lane >> 4;
    int m0 = blockIdx.x * 16;                 // 256 m-tiles
    int c0 = blockIdx.y * 256 + wave * 64;    // wave covers 64 c
    f32x4 acc[4];
    #pragma unroll
    for (int nt = 0; nt < 4; ++nt) acc[nt] = (f32x4){0.f, 0.f, 0.f, 0.f};
    const float* xp = x + (size_t)(m0 + m) * KIN + quad * 8;
    #pragma unroll
    for (int kk = 0; kk < 8; ++kk) {          // K = 256 = 8 * 32
        float4 xa = *(const float4*)(xp + kk * 32);
        float4 xb = *(const float4*)(xp + kk * 32 + 4);
        bf16x8 af;
        af[0] = (__bf16)xa.x; af[1] = (__bf16)xa.y; af[2] = (__bf16)xa.z; af[3] = (__bf16)xa.w;
        af[4] = (__bf16)xb.x; af[5] = (__bf16)xb.y; af[6] = (__bf16)xb.z; af[7] = (__bf16)xb.w;
        #pragma unroll
        for (int nt = 0; nt < 4; ++nt) {
            bf16x8 bf = *(const bf16x8*)(WT + (size_t)(c0 + nt * 16 + m) * KIN + kk * 32 + quad * 8);
            acc[nt] = __builtin_amdgcn_mfma_f32_16x16x32_bf16(af, bf, acc[nt], 0, 0, 0);
        }
    }
    // store transposed: lane owns col c = c0+nt*16+m; rows quad*4+reg
    #pragma unroll
    for (int nt = 0; nt < 4; ++nt) {
        bf16x4 o;
        #pragma unroll
        for (int e = 0; e < 4; ++e) o[e] = (__bf16)acc[nt][e];
        *(bf16x4*)(hbT + (size_t)(c0 + nt * 16 + m) * NN + m0 + quad * 4) = o;
    }
}

// ---------------- K2: ci[h][n], cj[h][n] ----------------
__global__ __launch_bounds__(256) void k_cicj(const __bf16* __restrict__ hbT,
                                              const float* __restrict__ ai,
                                              const float* __restrict__ aj,
                                              float* __restrict__ ci,
                                              float* __restrict__ cj) {
    int nl = threadIdx.x & 63;
    int h  = threadIdx.x >> 6;    // wave = head
    int n  = blockIdx.x * 64 + nl;
    float si = 0.f, sj = 0.f;
    for (int f = 0; f < OF; ++f) {
        int c = h * OF + f;
        float v = (float)hbT[(size_t)c * NN + n];   // coalesced across lanes
        si += v * ai[c];
        sj += v * aj[c];
    }
    ci[h * NN + n] = si;
    cj[h * NN + n] = sj;
}

// ---------------- K3: fused attention, full-j per block, fp32 out ---------
// grid (64 i-tiles, 4 heads); block 256 = 4 waves; wave = 16 i-rows.
__global__ __launch_bounds__(256) void k_attn(const float* __restrict__ adj,
                                              const __bf16* __restrict__ hbT,
                                              const float* __restrict__ ci,
                                              const float* __restrict__ cj,
                                              const float* __restrict__ bias,
                                              float* __restrict__ out) {
    __shared__ __bf16 vt[OF * 40];   // V tile 128f x 32j, stride 40 (2-way free)
    int lane = threadIdx.x & 63, wave = threadIdx.x >> 6;
    int m = lane & 15, quad = lane >> 4;
    int hd = blockIdx.y;
    int ibase = blockIdx.x * 64;
    int irow = ibase + wave * 16 + m;          // row this lane scores
    float cival = ci[hd * NN + irow];
    const float* adjp = adj + (size_t)irow * NN + quad * 8;
    const float* cjp  = cj + hd * NN + quad * 8;
    // V staging: thread -> (f row, 16-elt half)
    int fr = threadIdx.x >> 1, hh = threadIdx.x & 1;
    const __bf16* vsrc = hbT + (size_t)(hd * OF + fr) * NN + hh * 16;
    uint4* vdst = (uint4*)&vt[fr * 40 + hh * 16];

    f32x4 acc[8];
    #pragma unroll
    for (int nt = 0; nt < 8; ++nt) acc[nt] = (f32x4){0.f, 0.f, 0.f, 0.f};
    float denl = 0.f;

    uint4 v0 = *(const uint4*)(vsrc);
    uint4 v1 = *(const uint4*)(vsrc + 8);
    float4 pa0 = *(const float4*)(adjp);
    float4 pa1 = *(const float4*)(adjp + 4);
    for (int jt = 0; jt < 128; ++jt) {
        __syncthreads();                 // all waves done reading prev vt
        vdst[0] = v0;
        vdst[1] = v1;
        __syncthreads();                 // tile ready
        float4 ca0 = pa0, ca1 = pa1;
        float4 cj0 = *(const float4*)(cjp + jt * 32);
        float4 cj1 = *(const float4*)(cjp + jt * 32 + 4);
        if (jt < 127) {                  // prefetch next iter
            v0 = *(const uint4*)(vsrc + (jt + 1) * 32);
            v1 = *(const uint4*)(vsrc + (jt + 1) * 32 + 8);
            pa0 = *(const float4*)(adjp + (jt + 1) * 32);
            pa1 = *(const float4*)(adjp + (jt + 1) * 32 + 4);
        }
        float aa[8], cc[8];
        aa[0] = ca0.x; aa[1] = ca0.y; aa[2] = ca0.z; aa[3] = ca0.w;
        aa[4] = ca1.x; aa[5] = ca1.y; aa[6] = ca1.z; aa[7] = ca1.w;
        cc[0] = cj0.x; cc[1] = cj0.y; cc[2] = cj0.z; cc[3] = cj0.w;
        cc[4] = cj1.x; cc[5] = cj1.y; cc[6] = cj1.z; cc[7] = cj1.w;
        bf16x8 af;
        #pragma unroll
        for (int u = 0; u < 8; ++u) {
            float a = aa[u];
            float s = cival + cc[u];
            s = fmaxf(s, s * 0.2f);      // leaky_relu
            s *= a;
            float p = __expf(s);         // s in ~[-4,4]: shift-free softmax safe
            denl += p;
            af[u] = (__bf16)(p * a);
        }
        #pragma unroll
        for (int nt = 0; nt < 8; ++nt) {
            bf16x8 bf = *(const bf16x8*)(&vt[(nt * 16 + m) * 40 + quad * 8]);
            acc[nt] = __builtin_amdgcn_mfma_f32_16x16x32_bf16(af, bf, acc[nt], 0, 0, 0);
        }
    }
    // den: quads cover disjoint j mod 32 -> full butterfly over quad bits
    denl += __shfl_xor(denl, 16);
    denl += __shfl_xor(denl, 32);
    // epilogue: C/D row = quad*4+reg (i-local), col = m (f-local); fp32 out
    float dinv[4];
    #pragma unroll
    for (int reg = 0; reg < 4; ++reg)
        dinv[reg] = 1.0f / __shfl(denl, quad * 4 + reg);
    #pragma unroll
    for (int nt = 0; nt < 8; ++nt) {
        float b = bias[hd * OF + nt * 16 + m];
        #pragma unroll
        for (int reg = 0; reg < 4; ++reg) {
            int i = ibase + wave * 16 + quad * 4 + reg;
            out[(size_t)i * HF + hd * OF + nt * 16 + m] = acc[nt][reg] * dinv[reg] + b;
        }
    }
}

extern "C" void kernel_launch(void* const* d_in, const int* in_sizes, int n_in,
                              void* d_out, int out_size, void* d_ws, size_t ws_size,
                              hipStream_t stream) {
    const float* x    = (const float*)d_in[0];
    const float* adj  = (const float*)d_in[1];
    const float* W    = (const float*)d_in[2];
    const float* ai   = (const float*)d_in[3];
    const float* aj   = (const float*)d_in[4];
    const float* bias = (const float*)d_in[5];
    float* out = (float*)d_out;

    char* ws = (char*)d_ws;
    // ws: WT 256KB | hbT 4MB | ci 64KB | cj 64KB   (total ~4.4MB)
    __bf16* WT  = (__bf16*)(ws);
    __bf16* hbT = (__bf16*)(ws + (1 << 18));
    float*  ci  = (float*)(ws + (1 << 18) + (1 << 22));
    float*  cj  = (float*)(ws + (1 << 18) + (1 << 22) + (1 << 16));

    k_transpose_w<<<512, 256, 0, stream>>>(W, WT);
    k_gemm_h<<<dim3(256, 2), 256, 0, stream>>>(x, WT, hbT);
    k_cicj<<<64, 256, 0, stream>>>(hbT, ai, aj, ci, cj);
    k_attn<<<dim3(64, NHD), 256, 0, stream>>>(adj, hbT, ci, cj, bias, out);
}